// Round 1
// baseline (76.906 us; speedup 1.0000x reference)
//
#include <hip/hip_runtime.h>

#define NB_IMG   2048
#define GSQ      169            // 13*13
#define NCELLS   (NB_IMG * GSQ) // 346112
#define NCH      125
#define NANCH    5

// Accumulator layout in d_ws (16 doubles):
// [0..3]  coord sq sums (c=0..3, obj-masked)
// [4]     conf sq sum (obj)
// [5]     conf sq sum (noobj)
// [6..10] per-anchor class sq sums (obj-masked)
// [11..15] per-anchor obj counts

__global__ __launch_bounds__(256) void detloss_main(
    const float* __restrict__ det,
    const float* __restrict__ gt,
    const float* __restrict__ aw,
    const float* __restrict__ ah,
    double* __restrict__ acc)
{
    const int tid = blockIdx.x * 256 + threadIdx.x;   // exact: 1352*256 == NCELLS

    float S0 = 0.f, S1 = 0.f, S2 = 0.f, S3 = 0.f;     // coord
    float S4 = 0.f;                                   // conf obj
    float S5 = 0.f;                                   // conf noobj
    float Scls[NANCH] = {0.f, 0.f, 0.f, 0.f, 0.f};
    float Ccnt[NANCH] = {0.f, 0.f, 0.f, 0.f, 0.f};

    {
        const int b    = tid / GSQ;
        const int cell = tid - b * GSQ;
        const float* dp = det + (size_t)b * (NCH * GSQ) + cell;
        const float* gp = gt  + (size_t)b * (NCH * GSQ) + cell;

        // anchor-0 channels 0..3 drive the IoU for all anchors
        const float px = dp[0 * GSQ];
        const float py = dp[1 * GSQ];
        const float dw = dp[2 * GSQ];
        const float dh = dp[3 * GSQ];
        const float gx = gp[0 * GSQ];
        const float gy = gp[1 * GSQ];
        const float gw = gp[2 * GSQ];
        const float gh = gp[3 * GSQ];
        const float a2 = (gw - gx + 1.0f) * (gh - gy + 1.0f);

        #pragma unroll
        for (int k = 0; k < NANCH; ++k) {
            const float* dk = dp + k * 25 * GSQ;
            const float* gk = gp + k * 25 * GSQ;

            const float pw = dw * aw[k];
            const float ph = dh * ah[k];
            const float x1 = fmaxf(px, gx);
            const float y1 = fmaxf(py, gy);
            const float x2 = fminf(pw, gw);
            const float y2 = fminf(ph, gh);
            const float inter = (x2 - x1 + 1.0f) * (y2 - y1 + 1.0f);
            const float a1    = (pw - px + 1.0f) * (ph - py + 1.0f);
            const float iou   = inter / (a1 + a2 - inter);

            const float g4   = gk[4 * GSQ];
            const float conf = dk[4 * GSQ] * (iou >= 0.0f ? iou : 0.0f); // NaN -> 0 like jnp.where
            const float d4   = conf - g4;
            const float d4sq = d4 * d4;
            const bool  obj  = (g4 == 1.0f);
            const float m    = obj ? 1.0f : 0.0f;

            float dd;
            dd = dk[0 * GSQ] - gk[0 * GSQ]; S0 += m * dd * dd;
            dd = dk[1 * GSQ] - gk[1 * GSQ]; S1 += m * dd * dd;
            dd = dk[2 * GSQ] - gk[2 * GSQ]; S2 += m * dd * dd;
            dd = dk[3 * GSQ] - gk[3 * GSQ]; S3 += m * dd * dd;

            // selects (not mask-mul): d4sq may be huge; avoid inf*0
            S4 += obj ? d4sq : 0.0f;
            S5 += obj ? 0.0f : d4sq;

            float sc = 0.0f;
            #pragma unroll
            for (int j = 0; j < 20; ++j) {
                dd = dk[(5 + j) * GSQ] - gk[(5 + j) * GSQ];
                sc += dd * dd;
            }
            Scls[k] += m * sc;
            Ccnt[k] += m;
        }
    }

    // ---- block reduction of 16 partials ----
    float vals[16] = {S0, S1, S2, S3, S4, S5,
                      Scls[0], Scls[1], Scls[2], Scls[3], Scls[4],
                      Ccnt[0], Ccnt[1], Ccnt[2], Ccnt[3], Ccnt[4]};

    #pragma unroll
    for (int i = 0; i < 16; ++i) {
        #pragma unroll
        for (int off = 32; off > 0; off >>= 1)
            vals[i] += __shfl_down(vals[i], off, 64);
    }

    __shared__ float part[4][16];
    const int wave = threadIdx.x >> 6;
    const int lane = threadIdx.x & 63;
    if (lane == 0) {
        #pragma unroll
        for (int i = 0; i < 16; ++i) part[wave][i] = vals[i];
    }
    __syncthreads();
    if (threadIdx.x < 16) {
        const float s = part[0][threadIdx.x] + part[1][threadIdx.x] +
                        part[2][threadIdx.x] + part[3][threadIdx.x];
        atomicAdd(&acc[threadIdx.x], (double)s);
    }
}

__global__ void detloss_final(const double* __restrict__ acc, float* __restrict__ out)
{
    if (threadIdx.x == 0 && blockIdx.x == 0) {
        const double cnt = acc[11] + acc[12] + acc[13] + acc[14] + acc[15];
        const double coord = (cnt > 0.0) ? (acc[0] + acc[1] + acc[2] + acc[3]) / cnt : 0.0;
        const double s4    = (cnt > 0.0) ? acc[4] / cnt : 0.0;
        const double obj_loss = 5.0 * coord + s4;

        const double cntno  = (double)NCELLS * (double)NANCH - cnt;
        const double no_obj = (cntno > 0.0) ? 0.5 * acc[5] / cntno : 0.0;

        double confsum = 0.0;
        for (int k = 0; k < NANCH; ++k) {
            const double ck = acc[11 + k];
            if (ck > 0.0) confsum += acc[6 + k] / ck;
        }
        const double loss = obj_loss + no_obj + confsum;
        out[0] = (float)loss;
        out[1] = (float)obj_loss;
        out[2] = (float)no_obj;
        out[3] = (float)confsum;
    }
}

extern "C" void kernel_launch(void* const* d_in, const int* in_sizes, int n_in,
                              void* d_out, int out_size, void* d_ws, size_t ws_size,
                              hipStream_t stream)
{
    const float* det = (const float*)d_in[0];
    const float* gt  = (const float*)d_in[1];
    const float* aw  = (const float*)d_in[2];
    const float* ah  = (const float*)d_in[3];
    double* acc = (double*)d_ws;
    float*  out = (float*)d_out;

    hipMemsetAsync(acc, 0, 16 * sizeof(double), stream);
    detloss_main<<<NCELLS / 256, 256, 0, stream>>>(det, gt, aw, ah, acc);
    detloss_final<<<1, 64, 0, stream>>>(acc, out);
}